// Round 1
// baseline (4517.165 us; speedup 1.0000x reference)
//
#include <hip/hip_runtime.h>
#include <stdint.h>
#include <stddef.h>

// W4A8 fake-quant SwiGLU MLP for MI355X (gfx950).
// Exact-integer reformulation: fake-quant values are int*scale, so every
// matmul is an int8 x int4 integer GEMM (exact in i32/f32) times rank-1 scales.
// GEMMs use mfma_i32_16x16x64_i8 with m97-style 128x128 tiles + global_load_lds.

using i32x4 = __attribute__((ext_vector_type(4))) int;

#define BM 128
#define BN 128
#define BK 64

__device__ __forceinline__ void gl2lds16(const void* gptr, void* lptr) {
  __builtin_amdgcn_global_load_lds(
      (const __attribute__((address_space(1))) uint32_t*)gptr,
      (__attribute__((address_space(3))) uint32_t*)lptr, 16, 0, 0);
}

__global__ void init_habs_kernel(unsigned int* __restrict__ habs, int n) {
  int i = blockIdx.x * blockDim.x + threadIdx.x;
  if (i < n) habs[i] = 0u;
}

// Per-row symmetric fake-quant: scale = max(absmax/qmax, 1e-8),
// q = clip(rintf(v/scale), qmin, qmax). rintf == RNE == jnp.round.
__global__ void quant_rows_kernel(const float* __restrict__ src,
                                  int8_t* __restrict__ dst,
                                  float* __restrict__ scales,
                                  int cols, float qmax, float qmin) {
  const int row = blockIdx.x;
  const int n4 = cols >> 2;
  const float4* s4 = (const float4*)(src + (size_t)row * cols);
  float amax = 0.0f;
  for (int i = threadIdx.x; i < n4; i += blockDim.x) {
    float4 v = s4[i];
    amax = fmaxf(amax, fmaxf(fmaxf(fabsf(v.x), fabsf(v.y)),
                             fmaxf(fabsf(v.z), fabsf(v.w))));
  }
#pragma unroll
  for (int off = 32; off > 0; off >>= 1)
    amax = fmaxf(amax, __shfl_xor(amax, off, 64));
  __shared__ float wmax[4];
  if ((threadIdx.x & 63) == 0) wmax[threadIdx.x >> 6] = amax;
  __syncthreads();
  const float scale =
      fmaxf(fmaxf(fmaxf(wmax[0], wmax[1]), fmaxf(wmax[2], wmax[3])) / qmax,
            1e-8f);
  if (threadIdx.x == 0) scales[row] = scale;
  char4* d4 = (char4*)(dst + (size_t)row * cols);
  for (int i = threadIdx.x; i < n4; i += blockDim.x) {
    float4 v = s4[i];
    char4 q;
    q.x = (char)(int)fminf(fmaxf(rintf(v.x / scale), qmin), qmax);
    q.y = (char)(int)fminf(fmaxf(rintf(v.y / scale), qmin), qmax);
    q.z = (char)(int)fminf(fmaxf(rintf(v.z / scale), qmin), qmax);
    q.w = (char)(int)fminf(fmaxf(rintf(v.w / scale), qmin), qmax);
    d4[i] = q;
  }
}

__global__ void quant_h_kernel(const float* __restrict__ h,
                               int8_t* __restrict__ hq,
                               const unsigned int* __restrict__ habs,
                               int cols) {
  const int row = blockIdx.x;
  const float scale = fmaxf(__uint_as_float(habs[row]) / 127.0f, 1e-8f);
  const int n4 = cols >> 2;
  const float4* s4 = (const float4*)(h + (size_t)row * cols);
  char4* d4 = (char4*)(hq + (size_t)row * cols);
  for (int i = threadIdx.x; i < n4; i += blockDim.x) {
    float4 v = s4[i];
    char4 q;
    q.x = (char)(int)fminf(fmaxf(rintf(v.x / scale), -128.0f), 127.0f);
    q.y = (char)(int)fminf(fmaxf(rintf(v.y / scale), -128.0f), 127.0f);
    q.z = (char)(int)fminf(fmaxf(rintf(v.z / scale), -128.0f), 127.0f);
    q.w = (char)(int)fminf(fmaxf(rintf(v.w / scale), -128.0f), 127.0f);
    d4[i] = q;
  }
}

// Fused gate+up GEMM: acc_g = xq @ Wg^T, acc_u = xq @ Wu^T (int32 exact),
// epilogue h = silu(acc_g*sx*swg) * (acc_u*sx*swu), row absmax via atomicMax.
__global__ __launch_bounds__(256, 2) void gemm1_kernel(
    const int8_t* __restrict__ xq, const int8_t* __restrict__ wgq,
    const int8_t* __restrict__ wuq, const float* __restrict__ sx,
    const float* __restrict__ swg, const float* __restrict__ swu,
    float* __restrict__ hbuf, unsigned int* __restrict__ habs,
    int M, int N, int K) {
  __shared__ __align__(16) int8_t sA[BM * BK];
  __shared__ __align__(16) int8_t sBg[BN * BK];
  __shared__ __align__(16) int8_t sBu[BN * BK];

  const int tid = threadIdx.x;
  const int lane = tid & 63;
  const int quad = lane >> 4;
  const int l16 = lane & 15;
  const int wave = tid >> 6;
  const int wm = wave >> 1;
  const int wn = wave & 1;
  const int m0 = blockIdx.y * BM;
  const int n0 = blockIdx.x * BN;

  i32x4 accg[4][4] = {};
  i32x4 accu[4][4] = {};

  for (int k0 = 0; k0 < K; k0 += BK) {
#pragma unroll
    for (int it = 0; it < 2; ++it) {
      const int c = tid + it * 256;   // 512 16B chunks per 128x64 tile
      const int r = c >> 2;
      const int kc = (c & 3) << 4;
      gl2lds16(xq  + (size_t)(m0 + r) * K + (k0 + kc), sA  + c * 16);
      gl2lds16(wgq + (size_t)(n0 + r) * K + (k0 + kc), sBg + c * 16);
      gl2lds16(wuq + (size_t)(n0 + r) * K + (k0 + kc), sBu + c * 16);
    }
    __syncthreads();

    i32x4 af[4];
#pragma unroll
    for (int i = 0; i < 4; ++i)
      af[i] = *(const i32x4*)(sA + (wm * 64 + i * 16 + l16) * BK + quad * 16);
#pragma unroll
    for (int j = 0; j < 4; ++j) {
      const int nrow = wn * 64 + j * 16 + l16;
      i32x4 bg = *(const i32x4*)(sBg + nrow * BK + quad * 16);
      i32x4 bu = *(const i32x4*)(sBu + nrow * BK + quad * 16);
#pragma unroll
      for (int i = 0; i < 4; ++i) {
        accg[i][j] = __builtin_amdgcn_mfma_i32_16x16x64_i8(af[i], bg, accg[i][j], 0, 0, 0);
        accu[i][j] = __builtin_amdgcn_mfma_i32_16x16x64_i8(af[i], bu, accu[i][j], 0, 0, 0);
      }
    }
    __syncthreads();
  }

#pragma unroll
  for (int i = 0; i < 4; ++i) {
#pragma unroll
    for (int r = 0; r < 4; ++r) {
      const int row = m0 + wm * 64 + i * 16 + quad * 4 + r;
      const float s_x = sx[row];
      float hmax = 0.0f;
#pragma unroll
      for (int j = 0; j < 4; ++j) {
        const int col = n0 + wn * 64 + j * 16 + l16;
        const float g = (float)accg[i][j][r] * s_x * swg[col];
        const float u = (float)accu[i][j][r] * s_x * swu[col];
        const float hv = (g / (1.0f + expf(-g))) * u;  // silu(g)*u
        hbuf[(size_t)row * N + col] = hv;
        hmax = fmaxf(hmax, fabsf(hv));
      }
      atomicMax(&habs[row], __float_as_uint(hmax));  // f32>=0 orders as uint
    }
  }
}

// Down-projection GEMM: out = (hq @ Wd^T) * sh[m] * swd[n]
__global__ __launch_bounds__(256, 2) void gemm2_kernel(
    const int8_t* __restrict__ hq, const int8_t* __restrict__ wdq,
    const unsigned int* __restrict__ habs, const float* __restrict__ swd,
    float* __restrict__ out, int M, int N, int K) {
  __shared__ __align__(16) int8_t sA[BM * BK];
  __shared__ __align__(16) int8_t sB[BN * BK];

  const int tid = threadIdx.x;
  const int lane = tid & 63;
  const int quad = lane >> 4;
  const int l16 = lane & 15;
  const int wave = tid >> 6;
  const int wm = wave >> 1;
  const int wn = wave & 1;
  const int m0 = blockIdx.y * BM;
  const int n0 = blockIdx.x * BN;

  i32x4 acc[4][4] = {};

  for (int k0 = 0; k0 < K; k0 += BK) {
#pragma unroll
    for (int it = 0; it < 2; ++it) {
      const int c = tid + it * 256;
      const int r = c >> 2;
      const int kc = (c & 3) << 4;
      gl2lds16(hq  + (size_t)(m0 + r) * K + (k0 + kc), sA + c * 16);
      gl2lds16(wdq + (size_t)(n0 + r) * K + (k0 + kc), sB + c * 16);
    }
    __syncthreads();

    i32x4 af[4];
#pragma unroll
    for (int i = 0; i < 4; ++i)
      af[i] = *(const i32x4*)(sA + (wm * 64 + i * 16 + l16) * BK + quad * 16);
#pragma unroll
    for (int j = 0; j < 4; ++j) {
      i32x4 bf = *(const i32x4*)(sB + (wn * 64 + j * 16 + l16) * BK + quad * 16);
#pragma unroll
      for (int i = 0; i < 4; ++i)
        acc[i][j] = __builtin_amdgcn_mfma_i32_16x16x64_i8(af[i], bf, acc[i][j], 0, 0, 0);
    }
    __syncthreads();
  }

#pragma unroll
  for (int i = 0; i < 4; ++i) {
#pragma unroll
    for (int r = 0; r < 4; ++r) {
      const int row = m0 + wm * 64 + i * 16 + quad * 4 + r;
      const float sh = fmaxf(__uint_as_float(habs[row]) / 127.0f, 1e-8f);
#pragma unroll
      for (int j = 0; j < 4; ++j) {
        const int col = n0 + wn * 64 + j * 16 + l16;
        out[(size_t)row * N + col] = (float)acc[i][j][r] * sh * swd[col];
      }
    }
  }
}

extern "C" void kernel_launch(void* const* d_in, const int* in_sizes, int n_in,
                              void* d_out, int out_size, void* d_ws, size_t ws_size,
                              hipStream_t stream) {
  const float* x  = (const float*)d_in[0];   // [2,2048,4096]
  const float* Wg = (const float*)d_in[1];   // [11008,4096]
  const float* Wu = (const float*)d_in[2];   // [11008,4096]
  const float* Wd = (const float*)d_in[3];   // [4096,11008]
  float* out = (float*)d_out;                // [2,2048,4096] f32

  const int M = 4096;   // B*S
  const int D = 4096;
  const int F = 11008;

  // workspace layout (~378 MB total), all offsets 16B-aligned
  uint8_t* ws = (uint8_t*)d_ws;
  size_t off = 0;
  int8_t* xq  = (int8_t*)(ws + off); off += (size_t)M * D;      // 16 MB
  int8_t* wgq = (int8_t*)(ws + off); off += (size_t)F * D;      // 45 MB
  int8_t* wuq = (int8_t*)(ws + off); off += (size_t)F * D;      // 45 MB
  int8_t* wdq = (int8_t*)(ws + off); off += (size_t)D * F;      // 45 MB
  int8_t* hq  = (int8_t*)(ws + off); off += (size_t)M * F;      // 45 MB
  float* hbuf = (float*)(ws + off);  off += (size_t)M * F * 4;  // 180 MB
  float* sx   = (float*)(ws + off);  off += (size_t)M * 4;
  float* swg  = (float*)(ws + off);  off += (size_t)F * 4;
  float* swu  = (float*)(ws + off);  off += (size_t)F * 4;
  float* swd  = (float*)(ws + off);  off += (size_t)D * 4;
  unsigned int* habs = (unsigned int*)(ws + off); off += (size_t)M * 4;

  hipLaunchKernelGGL(init_habs_kernel, dim3(16), dim3(256), 0, stream, habs, M);
  hipLaunchKernelGGL(quant_rows_kernel, dim3(M), dim3(256), 0, stream,
                     x, xq, sx, D, 127.0f, -128.0f);
  hipLaunchKernelGGL(quant_rows_kernel, dim3(F), dim3(256), 0, stream,
                     Wg, wgq, swg, D, 7.0f, -8.0f);
  hipLaunchKernelGGL(quant_rows_kernel, dim3(F), dim3(256), 0, stream,
                     Wu, wuq, swu, D, 7.0f, -8.0f);
  hipLaunchKernelGGL(quant_rows_kernel, dim3(D), dim3(256), 0, stream,
                     Wd, wdq, swd, F, 7.0f, -8.0f);
  hipLaunchKernelGGL(gemm1_kernel, dim3(F / BN, M / BM), dim3(256), 0, stream,
                     xq, wgq, wuq, sx, swg, swu, hbuf, habs, M, F, D);
  hipLaunchKernelGGL(quant_h_kernel, dim3(M), dim3(256), 0, stream,
                     hbuf, hq, habs, F);
  hipLaunchKernelGGL(gemm2_kernel, dim3(D / BN, M / BM), dim3(256), 0, stream,
                     hq, wdq, habs, swd, out, M, D, F);
}

// Round 2
// 3539.339 us; speedup vs baseline: 1.2763x; 1.2763x over previous
//
#include <hip/hip_runtime.h>
#include <stdint.h>
#include <stddef.h>

// W4A8 fake-quant SwiGLU MLP for MI355X (gfx950).
// Exact-integer reformulation: fake-quant values are int*scale, so every
// matmul is an int8 x int4 integer GEMM (exact in i32/f32) times rank-1 scales.
// GEMMs: mfma_i32_16x16x64_i8, 128x128 tiles, global_load_lds width-16,
// XOR-swizzled LDS (slot = (quad + (row>>1)) & 3) for conflict-free b128 reads.
// No atomics: h row-absmax is recomputed in quant_h (two-pass over the row).

using i32x4 = __attribute__((ext_vector_type(4))) int;

#define BM 128
#define BN 128
#define BK 64

__device__ __forceinline__ void gl2lds16(const void* gptr, void* lptr) {
  __builtin_amdgcn_global_load_lds(
      (const __attribute__((address_space(1))) uint32_t*)gptr,
      (__attribute__((address_space(3))) uint32_t*)lptr, 16, 0, 0);
}

// Per-row symmetric fake-quant: scale = max(absmax/qmax, 1e-8),
// q = clip(rintf(v/scale), qmin, qmax). rintf == RNE == jnp.round.
__global__ void quant_rows_kernel(const float* __restrict__ src,
                                  int8_t* __restrict__ dst,
                                  float* __restrict__ scales,
                                  int cols, float qmax, float qmin) {
  const int row = blockIdx.x;
  const int n4 = cols >> 2;
  const float4* s4 = (const float4*)(src + (size_t)row * cols);
  float amax = 0.0f;
  for (int i = threadIdx.x; i < n4; i += blockDim.x) {
    float4 v = s4[i];
    amax = fmaxf(amax, fmaxf(fmaxf(fabsf(v.x), fabsf(v.y)),
                             fmaxf(fabsf(v.z), fabsf(v.w))));
  }
#pragma unroll
  for (int off = 32; off > 0; off >>= 1)
    amax = fmaxf(amax, __shfl_xor(amax, off, 64));
  __shared__ float wmax[4];
  if ((threadIdx.x & 63) == 0) wmax[threadIdx.x >> 6] = amax;
  __syncthreads();
  const float scale =
      fmaxf(fmaxf(fmaxf(wmax[0], wmax[1]), fmaxf(wmax[2], wmax[3])) / qmax,
            1e-8f);
  if (threadIdx.x == 0) scales[row] = scale;
  char4* d4 = (char4*)(dst + (size_t)row * cols);
  for (int i = threadIdx.x; i < n4; i += blockDim.x) {
    float4 v = s4[i];
    char4 q;
    q.x = (char)(int)fminf(fmaxf(rintf(v.x / scale), qmin), qmax);
    q.y = (char)(int)fminf(fmaxf(rintf(v.y / scale), qmin), qmax);
    q.z = (char)(int)fminf(fmaxf(rintf(v.z / scale), qmin), qmax);
    q.w = (char)(int)fminf(fmaxf(rintf(v.w / scale), qmin), qmax);
    d4[i] = q;
  }
}

// Two-pass per-row quant of h: pass1 block-reduce absmax, pass2 quantize.
// Also writes sh[row] for gemm2's epilogue. No atomics anywhere.
__global__ void quant_h_kernel(const float* __restrict__ h,
                               int8_t* __restrict__ hq,
                               float* __restrict__ sh, int cols) {
  const int row = blockIdx.x;
  const int n4 = cols >> 2;
  const float4* s4 = (const float4*)(h + (size_t)row * cols);
  float amax = 0.0f;
  for (int i = threadIdx.x; i < n4; i += blockDim.x) {
    float4 v = s4[i];
    amax = fmaxf(amax, fmaxf(fmaxf(fabsf(v.x), fabsf(v.y)),
                             fmaxf(fabsf(v.z), fabsf(v.w))));
  }
#pragma unroll
  for (int off = 32; off > 0; off >>= 1)
    amax = fmaxf(amax, __shfl_xor(amax, off, 64));
  __shared__ float wmax[4];
  if ((threadIdx.x & 63) == 0) wmax[threadIdx.x >> 6] = amax;
  __syncthreads();
  const float scale =
      fmaxf(fmaxf(fmaxf(wmax[0], wmax[1]), fmaxf(wmax[2], wmax[3])) / 127.0f,
            1e-8f);
  if (threadIdx.x == 0) sh[row] = scale;
  char4* d4 = (char4*)(hq + (size_t)row * cols);
  for (int i = threadIdx.x; i < n4; i += blockDim.x) {
    float4 v = s4[i];
    char4 q;
    q.x = (char)(int)fminf(fmaxf(rintf(v.x / scale), -128.0f), 127.0f);
    q.y = (char)(int)fminf(fmaxf(rintf(v.y / scale), -128.0f), 127.0f);
    q.z = (char)(int)fminf(fmaxf(rintf(v.z / scale), -128.0f), 127.0f);
    q.w = (char)(int)fminf(fmaxf(rintf(v.w / scale), -128.0f), 127.0f);
    d4[i] = q;
  }
}

// Fused gate+up GEMM: acc_g = xq @ Wg^T, acc_u = xq @ Wu^T (int32 exact),
// epilogue h = silu(acc_g*sx*swg) * (acc_u*sx*swu) -> hbuf (f32).
__global__ __launch_bounds__(256, 4) void gemm1_kernel(
    const int8_t* __restrict__ xq, const int8_t* __restrict__ wgq,
    const int8_t* __restrict__ wuq, const float* __restrict__ sx,
    const float* __restrict__ swg, const float* __restrict__ swu,
    float* __restrict__ hbuf, int M, int N, int K) {
  __shared__ __align__(16) int8_t sA[BM * BK];
  __shared__ __align__(16) int8_t sBg[BN * BK];
  __shared__ __align__(16) int8_t sBu[BN * BK];

  const int tid = threadIdx.x;
  const int lane = tid & 63;
  const int quad = lane >> 4;
  const int l16 = lane & 15;
  const int wave = tid >> 6;
  const int wm = wave >> 1;
  const int wn = wave & 1;
  const int m0 = blockIdx.y * BM;
  const int n0 = blockIdx.x * BN;

  i32x4 accg[4][4] = {};
  i32x4 accu[4][4] = {};

  for (int k0 = 0; k0 < K; k0 += BK) {
#pragma unroll
    for (int it = 0; it < 2; ++it) {
      const int c = tid + it * 256;   // 512 16B chunks per 128x64 tile
      const int r = c >> 2;           // tile row
      const int s = c & 3;            // LDS slot within row
      const int kc = ((s - (r >> 1)) & 3) << 4;  // XOR-swizzled source chunk
      gl2lds16(xq  + (size_t)(m0 + r) * K + (k0 + kc), sA  + c * 16);
      gl2lds16(wgq + (size_t)(n0 + r) * K + (k0 + kc), sBg + c * 16);
      gl2lds16(wuq + (size_t)(n0 + r) * K + (k0 + kc), sBu + c * 16);
    }
    __syncthreads();

    i32x4 af[4];
#pragma unroll
    for (int i = 0; i < 4; ++i) {
      const int ar = wm * 64 + i * 16 + l16;
      af[i] = *(const i32x4*)(sA + ar * BK + (((quad + (ar >> 1)) & 3) << 4));
    }
#pragma unroll
    for (int j = 0; j < 4; ++j) {
      const int br = wn * 64 + j * 16 + l16;
      const int bo = br * BK + (((quad + (br >> 1)) & 3) << 4);
      i32x4 bg = *(const i32x4*)(sBg + bo);
      i32x4 bu = *(const i32x4*)(sBu + bo);
#pragma unroll
      for (int i = 0; i < 4; ++i) {
        accg[i][j] = __builtin_amdgcn_mfma_i32_16x16x64_i8(af[i], bg, accg[i][j], 0, 0, 0);
        accu[i][j] = __builtin_amdgcn_mfma_i32_16x16x64_i8(af[i], bu, accu[i][j], 0, 0, 0);
      }
    }
    __syncthreads();
  }

  float sg[4], su[4];
#pragma unroll
  for (int j = 0; j < 4; ++j) {
    const int col = n0 + wn * 64 + j * 16 + l16;
    sg[j] = swg[col];
    su[j] = swu[col];
  }
#pragma unroll
  for (int i = 0; i < 4; ++i) {
#pragma unroll
    for (int r = 0; r < 4; ++r) {
      const int row = m0 + wm * 64 + i * 16 + quad * 4 + r;
      const float s_x = sx[row];
#pragma unroll
      for (int j = 0; j < 4; ++j) {
        const int col = n0 + wn * 64 + j * 16 + l16;
        const float g = (float)accg[i][j][r] * s_x * sg[j];
        const float u = (float)accu[i][j][r] * s_x * su[j];
        hbuf[(size_t)row * N + col] = (g / (1.0f + expf(-g))) * u;  // silu(g)*u
      }
    }
  }
}

// Down-projection GEMM: out = (hq @ Wd^T) * sh[m] * swd[n]
__global__ __launch_bounds__(256, 4) void gemm2_kernel(
    const int8_t* __restrict__ hq, const int8_t* __restrict__ wdq,
    const float* __restrict__ sh, const float* __restrict__ swd,
    float* __restrict__ out, int M, int N, int K) {
  __shared__ __align__(16) int8_t sA[BM * BK];
  __shared__ __align__(16) int8_t sB[BN * BK];

  const int tid = threadIdx.x;
  const int lane = tid & 63;
  const int quad = lane >> 4;
  const int l16 = lane & 15;
  const int wave = tid >> 6;
  const int wm = wave >> 1;
  const int wn = wave & 1;
  const int m0 = blockIdx.y * BM;
  const int n0 = blockIdx.x * BN;

  i32x4 acc[4][4] = {};

  for (int k0 = 0; k0 < K; k0 += BK) {
#pragma unroll
    for (int it = 0; it < 2; ++it) {
      const int c = tid + it * 256;
      const int r = c >> 2;
      const int s = c & 3;
      const int kc = ((s - (r >> 1)) & 3) << 4;
      gl2lds16(hq  + (size_t)(m0 + r) * K + (k0 + kc), sA + c * 16);
      gl2lds16(wdq + (size_t)(n0 + r) * K + (k0 + kc), sB + c * 16);
    }
    __syncthreads();

    i32x4 af[4];
#pragma unroll
    for (int i = 0; i < 4; ++i) {
      const int ar = wm * 64 + i * 16 + l16;
      af[i] = *(const i32x4*)(sA + ar * BK + (((quad + (ar >> 1)) & 3) << 4));
    }
#pragma unroll
    for (int j = 0; j < 4; ++j) {
      const int br = wn * 64 + j * 16 + l16;
      i32x4 bf = *(const i32x4*)(sB + br * BK + (((quad + (br >> 1)) & 3) << 4));
#pragma unroll
      for (int i = 0; i < 4; ++i)
        acc[i][j] = __builtin_amdgcn_mfma_i32_16x16x64_i8(af[i], bf, acc[i][j], 0, 0, 0);
    }
    __syncthreads();
  }

  float sn[4];
#pragma unroll
  for (int j = 0; j < 4; ++j) sn[j] = swd[n0 + wn * 64 + j * 16 + l16];
#pragma unroll
  for (int i = 0; i < 4; ++i) {
#pragma unroll
    for (int r = 0; r < 4; ++r) {
      const int row = m0 + wm * 64 + i * 16 + quad * 4 + r;
      const float s_m = sh[row];
#pragma unroll
      for (int j = 0; j < 4; ++j) {
        const int col = n0 + wn * 64 + j * 16 + l16;
        out[(size_t)row * N + col] = (float)acc[i][j][r] * s_m * sn[j];
      }
    }
  }
}

extern "C" void kernel_launch(void* const* d_in, const int* in_sizes, int n_in,
                              void* d_out, int out_size, void* d_ws, size_t ws_size,
                              hipStream_t stream) {
  const float* x  = (const float*)d_in[0];   // [2,2048,4096]
  const float* Wg = (const float*)d_in[1];   // [11008,4096]
  const float* Wu = (const float*)d_in[2];   // [11008,4096]
  const float* Wd = (const float*)d_in[3];   // [4096,11008]
  float* out = (float*)d_out;                // [2,2048,4096] f32

  const int M = 4096;   // B*S
  const int D = 4096;
  const int F = 11008;

  // workspace layout (~378 MB total), all offsets 16B-aligned
  uint8_t* ws = (uint8_t*)d_ws;
  size_t off = 0;
  int8_t* xq  = (int8_t*)(ws + off); off += (size_t)M * D;      // 16 MB
  int8_t* wgq = (int8_t*)(ws + off); off += (size_t)F * D;      // 45 MB
  int8_t* wuq = (int8_t*)(ws + off); off += (size_t)F * D;      // 45 MB
  int8_t* wdq = (int8_t*)(ws + off); off += (size_t)D * F;      // 45 MB
  int8_t* hq  = (int8_t*)(ws + off); off += (size_t)M * F;      // 45 MB
  float* hbuf = (float*)(ws + off);  off += (size_t)M * F * 4;  // 180 MB
  float* sx   = (float*)(ws + off);  off += (size_t)M * 4;
  float* swg  = (float*)(ws + off);  off += (size_t)F * 4;
  float* swu  = (float*)(ws + off);  off += (size_t)F * 4;
  float* swd  = (float*)(ws + off);  off += (size_t)D * 4;
  float* sh   = (float*)(ws + off);  off += (size_t)M * 4;

  hipLaunchKernelGGL(quant_rows_kernel, dim3(M), dim3(256), 0, stream,
                     x, xq, sx, D, 127.0f, -128.0f);
  hipLaunchKernelGGL(quant_rows_kernel, dim3(F), dim3(256), 0, stream,
                     Wg, wgq, swg, D, 7.0f, -8.0f);
  hipLaunchKernelGGL(quant_rows_kernel, dim3(F), dim3(256), 0, stream,
                     Wu, wuq, swu, D, 7.0f, -8.0f);
  hipLaunchKernelGGL(quant_rows_kernel, dim3(D), dim3(256), 0, stream,
                     Wd, wdq, swd, F, 7.0f, -8.0f);
  hipLaunchKernelGGL(gemm1_kernel, dim3(F / BN, M / BM), dim3(256), 0, stream,
                     xq, wgq, wuq, sx, swg, swu, hbuf, M, F, D);
  hipLaunchKernelGGL(quant_h_kernel, dim3(M), dim3(256), 0, stream,
                     hbuf, hq, sh, F);
  hipLaunchKernelGGL(gemm2_kernel, dim3(D / BN, M / BM), dim3(256), 0, stream,
                     hq, wdq, sh, swd, out, M, D, F);
}